// Round 1
// baseline (231.179 us; speedup 1.0000x reference)
//
#include <hip/hip_runtime.h>

#define DEV __device__ __forceinline__

typedef __attribute__((ext_vector_type(8))) __bf16 bf16x8;
typedef __attribute__((ext_vector_type(4))) float f32x4;
typedef __attribute__((ext_vector_type(4))) unsigned short u16x4;
typedef __attribute__((ext_vector_type(8))) unsigned short u16x8;

// RNE float -> bf16 bits
DEV unsigned short f2bf(float f) {
  unsigned u = __builtin_bit_cast(unsigned, f);
  u += 0x7FFFu + ((u >> 16) & 1u);
  return (unsigned short)(u >> 16);
}

DEV f32x4 mfma16(bf16x8 a, bf16x8 b, f32x4 c) {
  return __builtin_amdgcn_mfma_f32_16x16x32_bf16(a, b, c, 0, 0, 0);
}

// async global->LDS, 16B per lane; LDS dest must be wave-uniform base + lane*16
DEV void gload16(const void* g, void* l) {
  __builtin_amdgcn_global_load_lds(
      (const __attribute__((address_space(1))) unsigned int*)g,
      (__attribute__((address_space(3))) unsigned int*)l, 16, 0, 0);
}

// ---------------------------------------------------------------------------
// fp32 -> bf16 with XOR-swizzled storage: element (row,k) lives at ushort idx
//   row*1024 + ((k & ~7) ^ ((row&7)<<3)) + (k&7)
// (i.e. byte bits[6:4] ^= (row&7)<<4 — a granule permutation within each 128B
//  block, so linear global_load_lds staging + XOR'd ds_read is conflict-free.)
// cols fixed at 1024.
// ---------------------------------------------------------------------------
__global__ __launch_bounds__(256) void k_cvt_swz(const float* __restrict__ src,
                                                 unsigned short* __restrict__ dst,
                                                 int ng) {
  int g = blockIdx.x * 256 + threadIdx.x;
  if (g >= ng) return;
  int row = g >> 7, k8 = g & 127;
  const f32x4* s = (const f32x4*)(src + ((size_t)row << 10) + (k8 << 3));
  f32x4 a = s[0], b = s[1];
  u16x8 o;
  o[0] = f2bf(a[0]); o[1] = f2bf(a[1]); o[2] = f2bf(a[2]); o[3] = f2bf(a[3]);
  o[4] = f2bf(b[0]); o[5] = f2bf(b[1]); o[6] = f2bf(b[2]); o[7] = f2bf(b[3]);
  *(u16x8*)(dst + ((size_t)row << 10) + ((k8 << 3) ^ ((row & 7) << 3))) = o;
}

// ---------------------------------------------------------------------------
// Shared NT-GEMM mainloop: C(128x128) = A(128x1024) * B(128x1024)^T, bf16.
// A,B are swizzled-bf16 (see k_cvt_swz). 256 threads = 4 waves, each wave owns
// a 64x64 quadrant (wm=wid>>1, wn=wid&1) as 4x4 16x16x32 fragments. BK=64,
// single LDS buffer (A:16KB @0, B:16KB @16384), 2-barrier loop (m97 structure).
// ---------------------------------------------------------------------------
DEV void gemm_mainloop(const char* Ag, const char* Bg, char* lds,
                       int lane, int wid, f32x4 acc[4][4]) {
  int g4 = lane >> 4, r16 = lane & 15;
  int wm = wid >> 1, wn = wid & 1;
  int adA[2], adB[2];
#pragma unroll
  for (int ks = 0; ks < 2; ++ks) {
    int swz = ((ks * 4 + g4) ^ (lane & 7)) << 4;  // swizzled 16B-granule
    adA[ks] = (wm * 64 + r16) * 128 + swz;
    adB[ks] = 16384 + (wn * 64 + r16) * 128 + swz;
  }
  int o0 = wid * 4096 + lane * 16;
  for (int kt = 0; kt < 16; ++kt) {
    __syncthreads();  // prev compute done before overwrite
#pragma unroll
    for (int i = 0; i < 4; ++i) {
      int oo = o0 + i * 1024;
      int row = oo >> 7, inrow = oo & 127;
      size_t gofs = (size_t)row * 2048 + (size_t)kt * 128 + inrow;
      gload16(Ag + gofs, lds + oo);
      gload16(Bg + gofs, lds + 16384 + oo);
    }
    __syncthreads();  // drains vmcnt -> staged data visible
    bf16x8 af[2][4], bfr[2][4];
#pragma unroll
    for (int ks = 0; ks < 2; ++ks)
#pragma unroll
      for (int i = 0; i < 4; ++i) {
        af[ks][i]  = *(const bf16x8*)(lds + adA[ks] + i * 2048);
        bfr[ks][i] = *(const bf16x8*)(lds + adB[ks] + i * 2048);
      }
#pragma unroll
    for (int ks = 0; ks < 2; ++ks)
#pragma unroll
      for (int mi = 0; mi < 4; ++mi)
#pragma unroll
        for (int ni = 0; ni < 4; ++ni)
          acc[mi][ni] = mfma16(af[ks][mi], bfr[ks][ni], acc[mi][ni]);
  }
}

// ---------------------------------------------------------------------------
// QKV projection: grid 768 = 32 (bm) x 24 (bn over 3*1024 cols).
// Epilogue routes to Q,K [bh][s][hd] row-major bf16, V transposed [bh][hd][s].
// C/D layout (m89-verified): col = lane&15, row = (lane>>4)*4 + reg.
// ---------------------------------------------------------------------------
__global__ __launch_bounds__(256) void k_gemm_qkv(
    const unsigned short* __restrict__ xb,
    const unsigned short* __restrict__ Wqb, const unsigned short* __restrict__ Wkb,
    const unsigned short* __restrict__ Wvb,
    const float* __restrict__ bq, const float* __restrict__ bk,
    const float* __restrict__ bv,
    unsigned short* __restrict__ Qb, unsigned short* __restrict__ Kb,
    unsigned short* __restrict__ Vt) {
  __shared__ char lds[32768];
  int tid = threadIdx.x, lane = tid & 63, wid = tid >> 6;
  int bm = blockIdx.x & 31, bn = blockIdx.x >> 5;
  int r0 = bm * 128;
  int colT = bn * 128;
  int which = colT >> 10;          // 0=Q 1=K 2=V (block never straddles)
  int ncol = colT & 1023;
  const unsigned short* Wb = which == 0 ? Wqb : which == 1 ? Wkb : Wvb;
  f32x4 acc[4][4] = {};
  gemm_mainloop((const char*)xb + (size_t)r0 * 2048,
                (const char*)Wb + (size_t)ncol * 2048, lds, lane, wid, acc);
  int g4 = lane >> 4, r16 = lane & 15, wm = wid >> 1, wn = wid & 1;
  const float* bias = which == 0 ? bq : which == 1 ? bk : bv;
  int ncolw = ncol + wn * 64;
#pragma unroll
  for (int ni = 0; ni < 4; ++ni) {
    int gcol = ncolw + ni * 16 + r16;   // col within selected matrix
    float bvv = bias[gcol];
    int h = gcol >> 6, hd = gcol & 63;
#pragma unroll
    for (int mi = 0; mi < 4; ++mi) {
      int growb = r0 + wm * 64 + mi * 16 + g4 * 4;  // global row (b*2048+s)
      int bb = growb >> 11, s0 = growb & 2047;
      if (which == 2) {  // V transposed: [bh][hd][s]; 4 consecutive s -> 8B store
        u16x4 pk;
#pragma unroll
        for (int jj = 0; jj < 4; ++jj) pk[jj] = f2bf(acc[mi][ni][jj] + bvv);
        *(u16x4*)(Vt + ((size_t)(bb * 16 + h) * 64 + hd) * 2048 + s0) = pk;
      } else {
        unsigned short* dst = which == 0 ? Qb : Kb;
        size_t base = ((size_t)(bb * 16 + h) * 2048 + s0) * 64 + hd;
#pragma unroll
        for (int jj = 0; jj < 4; ++jj)
          dst[base + (size_t)jj * 64] = f2bf(acc[mi][ni][jj] + bvv);
      }
    }
  }
}

// ---------------------------------------------------------------------------
// Flash attention, causal. 1 wave per 16 q-rows, KVBLK=32.
// Block = 4 waves = one 64-row q-chunk of one (b,h); heavy chunks dispatched
// first (chunk = 31 - bid/32) for load balance. K/V read direct from global
// (L2-resident, 512KB/head). P round-trips through 112B-stride LDS (16B
// aligned, 2-way banks) to convert C-layout -> A-fragment layout.
// Output written bf16, pre-swizzled for the out-proj GEMM.
// ---------------------------------------------------------------------------
__global__ __launch_bounds__(256) void k_attn(
    const unsigned short* __restrict__ Q, const unsigned short* __restrict__ K,
    const unsigned short* __restrict__ Vt, unsigned short* __restrict__ ansb) {
  __shared__ char plds[4 * 1792];
  int tid = threadIdx.x, lane = tid & 63, wid = tid >> 6;
  int bid = blockIdx.x;
  int bh = bid & 31, chunk = 31 - (bid >> 5);
  int b = bh >> 4, h = bh & 15;
  int q0 = chunk * 64 + wid * 16;
  const unsigned short* Qb = Q + (size_t)(b * 16 + h) * (2048 * 64);
  const unsigned short* Kb = K + (size_t)(b * 16 + h) * (2048 * 64);
  const unsigned short* Vb = Vt + (size_t)(b * 16 + h) * (64 * 2048);
  int g4 = lane >> 4, r16 = lane & 15;
  bf16x8 qa0 = *(const bf16x8*)(Qb + (size_t)(q0 + r16) * 64 + g4 * 8);
  bf16x8 qa1 = *(const bf16x8*)(Qb + (size_t)(q0 + r16) * 64 + 32 + g4 * 8);
  f32x4 oacc[4] = {};
  float m_[4], l_[4];
#pragma unroll
  for (int jj = 0; jj < 4; ++jj) { m_[jj] = -1e30f; l_[jj] = 0.f; }
  char* Pw = plds + wid * 1792;
  int nkb = ((q0 + 15) >> 5) + 1;  // kv0_max <= q0 always (no all-masked rows)
  for (int kb = 0; kb < nkb; ++kb) {
    int kv0 = kb << 5;
    f32x4 st[2];
#pragma unroll
    for (int nt = 0; nt < 2; ++nt) {
      const unsigned short* kr = Kb + (size_t)(kv0 + nt * 16 + r16) * 64 + g4 * 8;
      bf16x8 kf0 = *(const bf16x8*)kr;
      bf16x8 kf1 = *(const bf16x8*)(kr + 32);
      f32x4 z = {};
      z = mfma16(qa0, kf0, z);
      st[nt] = mfma16(qa1, kf1, z);
    }
    float pm[4], alv[4], rs[4];
#pragma unroll
    for (int jj = 0; jj < 4; ++jj) {
      int row = q0 + g4 * 4 + jj;
#pragma unroll
      for (int nt = 0; nt < 2; ++nt) {
        int col = kv0 + nt * 16 + r16;
        float s = st[nt][jj] * 0.125f;  // 1/sqrt(64)
        st[nt][jj] = (col <= row) ? s : -1e30f;
      }
      pm[jj] = fmaxf(st[0][jj], st[1][jj]);
    }
#pragma unroll
    for (int msk = 1; msk <= 8; msk <<= 1)
#pragma unroll
      for (int jj = 0; jj < 4; ++jj)
        pm[jj] = fmaxf(pm[jj], __shfl_xor(pm[jj], msk, 64));
#pragma unroll
    for (int jj = 0; jj < 4; ++jj) {
      float nm = fmaxf(m_[jj], pm[jj]);
      alv[jj] = exp2f((m_[jj] - nm) * 1.44269504f);
      float p0 = exp2f((st[0][jj] - nm) * 1.44269504f);
      float p1 = exp2f((st[1][jj] - nm) * 1.44269504f);
      st[0][jj] = p0; st[1][jj] = p1;
      rs[jj] = p0 + p1;
      m_[jj] = nm;
      l_[jj] *= alv[jj];
    }
#pragma unroll
    for (int msk = 1; msk <= 8; msk <<= 1)
#pragma unroll
      for (int jj = 0; jj < 4; ++jj) rs[jj] += __shfl_xor(rs[jj], msk, 64);
#pragma unroll
    for (int jj = 0; jj < 4; ++jj) l_[jj] += rs[jj];
#pragma unroll
    for (int nh = 0; nh < 4; ++nh)
#pragma unroll
      for (int jj = 0; jj < 4; ++jj) oacc[nh][jj] *= alv[jj];
    // P (C-layout) -> LDS -> A-fragment layout
#pragma unroll
    for (int nt = 0; nt < 2; ++nt)
#pragma unroll
      for (int jj = 0; jj < 4; ++jj) {
        int r = g4 * 4 + jj, c = nt * 16 + r16;
        *(unsigned short*)(Pw + r * 112 + c * 2) = f2bf(st[nt][jj]);
      }
    asm volatile("s_waitcnt lgkmcnt(0)" ::: "memory");
    bf16x8 pf = *(const bf16x8*)(Pw + r16 * 112 + g4 * 16);
#pragma unroll
    for (int nh = 0; nh < 4; ++nh) {
      bf16x8 vf = *(const bf16x8*)(Vb + (size_t)(nh * 16 + r16) * 2048 + kv0 + g4 * 8);
      oacc[nh] = mfma16(pf, vf, oacc[nh]);
    }
  }
  float rl[4];
#pragma unroll
  for (int jj = 0; jj < 4; ++jj) rl[jj] = 1.f / l_[jj];
#pragma unroll
  for (int nh = 0; nh < 4; ++nh)
#pragma unroll
    for (int jj = 0; jj < 4; ++jj) {
      int rowg = (b << 11) + q0 + g4 * 4 + jj;
      int colg = (h << 6) + nh * 16 + r16;
      size_t idx = ((size_t)rowg << 10) + (colg ^ ((rowg & 7) << 3));
      ansb[idx] = f2bf(oacc[nh][jj] * rl[jj]);
    }
}

// ---------------------------------------------------------------------------
// Output projection: out(fp32) = ansb(4096x1024,swz) * Wo^T + bo. Grid 256.
// ---------------------------------------------------------------------------
__global__ __launch_bounds__(256) void k_gemm_out(
    const unsigned short* __restrict__ ansb, const unsigned short* __restrict__ Wob,
    const float* __restrict__ bo, float* __restrict__ out) {
  __shared__ char lds[32768];
  int tid = threadIdx.x, lane = tid & 63, wid = tid >> 6;
  int bm = blockIdx.x & 31, bn = blockIdx.x >> 5;
  int r0 = bm * 128, c0 = bn * 128;
  f32x4 acc[4][4] = {};
  gemm_mainloop((const char*)ansb + (size_t)r0 * 2048,
                (const char*)Wob + (size_t)c0 * 2048, lds, lane, wid, acc);
  int g4 = lane >> 4, r16 = lane & 15, wm = wid >> 1, wn = wid & 1;
#pragma unroll
  for (int ni = 0; ni < 4; ++ni) {
    int gcol = c0 + wn * 64 + ni * 16 + r16;
    float bvv = bo[gcol];
#pragma unroll
    for (int mi = 0; mi < 4; ++mi) {
      int growb = r0 + wm * 64 + mi * 16 + g4 * 4;
#pragma unroll
      for (int jj = 0; jj < 4; ++jj)
        out[(size_t)(growb + jj) * 1024 + gcol] = acc[mi][ni][jj] + bvv;
    }
  }
}

extern "C" void kernel_launch(void* const* d_in, const int* in_sizes, int n_in,
                              void* d_out, int out_size, void* d_ws, size_t ws_size,
                              hipStream_t stream) {
  const float* x  = (const float*)d_in[0];
  const float* Wq = (const float*)d_in[1];
  const float* bq = (const float*)d_in[2];
  const float* Wk = (const float*)d_in[3];
  const float* bk = (const float*)d_in[4];
  const float* Wv = (const float*)d_in[5];
  const float* bv = (const float*)d_in[6];
  const float* Wo = (const float*)d_in[7];
  const float* bo = (const float*)d_in[8];
  char* ws = (char*)d_ws;
  // Workspace map (40 MB total): ansb aliases xb (dead after QKV GEMM).
  unsigned short* xb   = (unsigned short*)(ws);                  // 8 MB
  unsigned short* ansb = (unsigned short*)(ws);                  // 8 MB (alias)
  unsigned short* Wqb  = (unsigned short*)(ws + (8u  << 20));    // 2 MB
  unsigned short* Wkb  = (unsigned short*)(ws + (10u << 20));    // 2 MB
  unsigned short* Wvb  = (unsigned short*)(ws + (12u << 20));    // 2 MB
  unsigned short* Wob  = (unsigned short*)(ws + (14u << 20));    // 2 MB
  unsigned short* Qb   = (unsigned short*)(ws + (16u << 20));    // 8 MB
  unsigned short* Kb   = (unsigned short*)(ws + (24u << 20));    // 8 MB
  unsigned short* Vt   = (unsigned short*)(ws + (32u << 20));    // 8 MB

  k_cvt_swz<<<2048, 256, 0, stream>>>(x,  xb,  524288);
  k_cvt_swz<<<512,  256, 0, stream>>>(Wq, Wqb, 131072);
  k_cvt_swz<<<512,  256, 0, stream>>>(Wk, Wkb, 131072);
  k_cvt_swz<<<512,  256, 0, stream>>>(Wv, Wvb, 131072);
  k_cvt_swz<<<512,  256, 0, stream>>>(Wo, Wob, 131072);
  k_gemm_qkv<<<768, 256, 0, stream>>>(xb, Wqb, Wkb, Wvb, bq, bk, bv, Qb, Kb, Vt);
  k_attn<<<1024, 256, 0, stream>>>(Qb, Kb, Vt, ansb);
  k_gemm_out<<<256, 256, 0, stream>>>(ansb, Wob, bo, (float*)d_out);
}

// Round 2
// 137.455 us; speedup vs baseline: 1.6819x; 1.6819x over previous
//
#include <hip/hip_runtime.h>

#define DEV __device__ __forceinline__

typedef __attribute__((ext_vector_type(8))) __bf16 bf16x8;
typedef __attribute__((ext_vector_type(4))) float f32x4;
typedef __attribute__((ext_vector_type(16))) float f32x16;
typedef __attribute__((ext_vector_type(4))) unsigned short u16x4;
typedef __attribute__((ext_vector_type(8))) unsigned short u16x8;

// RNE float -> bf16 bits
DEV unsigned short f2bf(float f) {
  unsigned u = __builtin_bit_cast(unsigned, f);
  u += 0x7FFFu + ((u >> 16) & 1u);
  return (unsigned short)(u >> 16);
}

DEV f32x4 mfma16(bf16x8 a, bf16x8 b, f32x4 c) {
  return __builtin_amdgcn_mfma_f32_16x16x32_bf16(a, b, c, 0, 0, 0);
}
DEV f32x16 mfma32(bf16x8 a, bf16x8 b, f32x16 c) {
  return __builtin_amdgcn_mfma_f32_32x32x16_bf16(a, b, c, 0, 0, 0);
}

// async global->LDS, 16B per lane; LDS dest must be wave-uniform base + lane*16
DEV void gload16(const void* g, void* l) {
  __builtin_amdgcn_global_load_lds(
      (const __attribute__((address_space(1))) unsigned int*)g,
      (__attribute__((address_space(3))) unsigned int*)l, 16, 0, 0);
}

// ---------------------------------------------------------------------------
// fp32 -> bf16 with XOR-swizzled storage: element (row,k) lives at ushort idx
//   row*1024 + ((k & ~7) ^ ((row&7)<<3)) + (k&7)
// ---------------------------------------------------------------------------
__global__ __launch_bounds__(256) void k_cvt_swz(const float* __restrict__ src,
                                                 unsigned short* __restrict__ dst,
                                                 int ng) {
  int g = blockIdx.x * 256 + threadIdx.x;
  if (g >= ng) return;
  int row = g >> 7, k8 = g & 127;
  const f32x4* s = (const f32x4*)(src + ((size_t)row << 10) + (k8 << 3));
  f32x4 a = s[0], b = s[1];
  u16x8 o;
  o[0] = f2bf(a[0]); o[1] = f2bf(a[1]); o[2] = f2bf(a[2]); o[3] = f2bf(a[3]);
  o[4] = f2bf(b[0]); o[5] = f2bf(b[1]); o[6] = f2bf(b[2]); o[7] = f2bf(b[3]);
  *(u16x8*)(dst + ((size_t)row << 10) + ((k8 << 3) ^ ((row & 7) << 3))) = o;
}

// ---------------------------------------------------------------------------
// Shared NT-GEMM mainloop (m97 structure), unchanged from round 1.
// ---------------------------------------------------------------------------
DEV void gemm_mainloop(const char* Ag, const char* Bg, char* lds,
                       int lane, int wid, f32x4 acc[4][4]) {
  int g4 = lane >> 4, r16 = lane & 15;
  int wm = wid >> 1, wn = wid & 1;
  int adA[2], adB[2];
#pragma unroll
  for (int ks = 0; ks < 2; ++ks) {
    int swz = ((ks * 4 + g4) ^ (lane & 7)) << 4;
    adA[ks] = (wm * 64 + r16) * 128 + swz;
    adB[ks] = 16384 + (wn * 64 + r16) * 128 + swz;
  }
  int o0 = wid * 4096 + lane * 16;
  for (int kt = 0; kt < 16; ++kt) {
    __syncthreads();
#pragma unroll
    for (int i = 0; i < 4; ++i) {
      int oo = o0 + i * 1024;
      int row = oo >> 7, inrow = oo & 127;
      size_t gofs = (size_t)row * 2048 + (size_t)kt * 128 + inrow;
      gload16(Ag + gofs, lds + oo);
      gload16(Bg + gofs, lds + 16384 + oo);
    }
    __syncthreads();
    bf16x8 af[2][4], bfr[2][4];
#pragma unroll
    for (int ks = 0; ks < 2; ++ks)
#pragma unroll
      for (int i = 0; i < 4; ++i) {
        af[ks][i]  = *(const bf16x8*)(lds + adA[ks] + i * 2048);
        bfr[ks][i] = *(const bf16x8*)(lds + adB[ks] + i * 2048);
      }
#pragma unroll
    for (int ks = 0; ks < 2; ++ks)
#pragma unroll
      for (int mi = 0; mi < 4; ++mi)
#pragma unroll
        for (int ni = 0; ni < 4; ++ni)
          acc[mi][ni] = mfma16(af[ks][mi], bfr[ks][ni], acc[mi][ni]);
  }
}

// ---------------------------------------------------------------------------
// QKV projection (unchanged): Q,K row-major [bh][s][64]; V transposed [bh][hd][s].
// ---------------------------------------------------------------------------
__global__ __launch_bounds__(256) void k_gemm_qkv(
    const unsigned short* __restrict__ xb,
    const unsigned short* __restrict__ Wqb, const unsigned short* __restrict__ Wkb,
    const unsigned short* __restrict__ Wvb,
    const float* __restrict__ bq, const float* __restrict__ bk,
    const float* __restrict__ bv,
    unsigned short* __restrict__ Qb, unsigned short* __restrict__ Kb,
    unsigned short* __restrict__ Vt) {
  __shared__ char lds[32768];
  int tid = threadIdx.x, lane = tid & 63, wid = tid >> 6;
  int bm = blockIdx.x & 31, bn = blockIdx.x >> 5;
  int r0 = bm * 128;
  int colT = bn * 128;
  int which = colT >> 10;
  int ncol = colT & 1023;
  const unsigned short* Wb = which == 0 ? Wqb : which == 1 ? Wkb : Wvb;
  f32x4 acc[4][4] = {};
  gemm_mainloop((const char*)xb + (size_t)r0 * 2048,
                (const char*)Wb + (size_t)ncol * 2048, lds, lane, wid, acc);
  int g4 = lane >> 4, r16 = lane & 15, wm = wid >> 1, wn = wid & 1;
  const float* bias = which == 0 ? bq : which == 1 ? bk : bv;
  int ncolw = ncol + wn * 64;
#pragma unroll
  for (int ni = 0; ni < 4; ++ni) {
    int gcol = ncolw + ni * 16 + r16;
    float bvv = bias[gcol];
    int h = gcol >> 6, hd = gcol & 63;
#pragma unroll
    for (int mi = 0; mi < 4; ++mi) {
      int growb = r0 + wm * 64 + mi * 16 + g4 * 4;
      int bb = growb >> 11, s0 = growb & 2047;
      if (which == 2) {
        u16x4 pk;
#pragma unroll
        for (int jj = 0; jj < 4; ++jj) pk[jj] = f2bf(acc[mi][ni][jj] + bvv);
        *(u16x4*)(Vt + ((size_t)(bb * 16 + h) * 64 + hd) * 2048 + s0) = pk;
      } else {
        unsigned short* dst = which == 0 ? Qb : Kb;
        size_t base = ((size_t)(bb * 16 + h) * 2048 + s0) * 64 + hd;
#pragma unroll
        for (int jj = 0; jj < 4; ++jj)
          dst[base + (size_t)jj * 64] = f2bf(acc[mi][ni][jj] + bvv);
      }
    }
  }
}

// ---------------------------------------------------------------------------
// Flash attention, causal — m214-style 32x32 swapped-QK^T structure.
// Block = 4 waves, each wave owns 32 q-rows (block = 128-row chunk of one bh).
// KVBLK=64. K/V staged in LDS (XOR-swizzled via pre-swizzled global source),
// double-buffered, ONE barrier per tile (vmcnt(0)-before-barrier completes the
// global_load_lds issued one tile ahead).
// Swapped QK^T: S^T = mfma32(A=K-rows, B=Q-rows): lane owns q = lane&31,
// kv = 32s + (r&3) + 8(r>>2) + 4*(lane>>5). Row-max = in-lane tree + 1 shfl.
// Defer-max (THR=8): rescale path (LDS alv broadcast) is rare.
// P->bf16 A-frags in-register: cvt_pk pairs + cross-half shfl_xor(32).
// O: lane = hd (col), regs = q; final 1/l broadcast via per-wave LDS strip.
// ---------------------------------------------------------------------------
__global__ __launch_bounds__(256) void k_attn(
    const unsigned short* __restrict__ Q, const unsigned short* __restrict__ K,
    const unsigned short* __restrict__ Vt, unsigned short* __restrict__ ansb) {
  __shared__ char lds[2 * 16384 + 512];
  const float SCL = 0.18033688f;  // 0.125 * log2(e)
  int tid = threadIdx.x, lane = tid & 63, wid = tid >> 6;
  int l31 = lane & 31, hi = lane >> 5;
  int bid = blockIdx.x;
  int bh = bid & 31, chunk = 15 - (bid >> 5);  // heavy chunks dispatched first
  int b = bh >> 4, h = bh & 15;
  int q0 = chunk * 128 + wid * 32;  // within-sequence base row of this wave
  int nt = 2 * chunk + 2;           // kv tiles of 64 for this block
  const unsigned short* Qh = Q + (size_t)bh * (2048 * 64);
  const char* Kg = (const char*)(K + (size_t)bh * (2048 * 64));
  const char* Vg = (const char*)(Vt + (size_t)bh * (64 * 2048));
  char* wb = lds + 32768 + wid * 128;  // per-wave broadcast strip

  // staging constants: LDS byte o -> (row=o>>7, cswz=o&127); source col = cswz^swz(row)
  int ldo0 = tid * 16, ldo1 = tid * 16 + 4096;
  int row0 = ldo0 >> 7, c0 = ldo0 & 127;
  int row1 = ldo1 >> 7, c1 = ldo1 & 127;
  int sc0 = c0 ^ ((row0 & 7) << 4), sc1 = c1 ^ ((row1 & 7) << 4);
  int ko0 = row0 * 128 + sc0, ko1 = row1 * 128 + sc1;   // K: row = kv
  int vo0 = row0 * 4096 + sc0, vo1 = row1 * 4096 + sc1; // V: row = hd (Vt stride 2048*2B)

  // Q fragments (B-operand): col=lane&31=q, k=(lane>>5)*8+j per 16-k step
  bf16x8 qf[4];
#pragma unroll
  for (int ks = 0; ks < 4; ++ks)
    qf[ks] = *(const bf16x8*)(Qh + (size_t)(q0 + l31) * 64 + ks * 16 + hi * 8);

  f32x16 O0 = {}, O1 = {};
  float m2 = -1e30f, l = 0.f;
  int swzl = (l31 & 7) << 4;
  int hioff = hi * 16;

  // prologue: stage tile 0 into buffer 0
  gload16(Kg + ko0, lds + ldo0);
  gload16(Kg + ko1, lds + ldo1);
  gload16(Vg + vo0, lds + 8192 + ldo0);
  gload16(Vg + vo1, lds + 8192 + ldo1);

  for (int t = 0; t < nt; ++t) {
    __syncthreads();  // staged tile t complete (vmcnt0 drain); prior reads done
    if (t + 1 < nt) {
      size_t kv1 = (size_t)(t + 1) * 64;
      int pb = ((t + 1) & 1) * 16384;
      gload16(Kg + kv1 * 128 + ko0, lds + pb + ldo0);
      gload16(Kg + kv1 * 128 + ko1, lds + pb + ldo1);
      gload16(Vg + kv1 * 2 + vo0, lds + pb + 8192 + ldo0);
      gload16(Vg + kv1 * 2 + vo1, lds + pb + 8192 + ldo1);
    }
    int kv0 = t * 64;
    if (kv0 <= q0 + 31) {  // wave active for this tile
      const char* KL = lds + (t & 1) * 16384;
      const char* VL = KL + 8192;
      f32x16 s0 = {}, s1 = {};
      __builtin_amdgcn_s_setprio(1);
#pragma unroll
      for (int ks = 0; ks < 4; ++ks) {
        bf16x8 kf0 = *(const bf16x8*)(KL + l31 * 128 + ((ks * 32 + hioff) ^ swzl));
        bf16x8 kf1 = *(const bf16x8*)(KL + (32 + l31) * 128 + ((ks * 32 + hioff) ^ swzl));
        s0 = mfma32(kf0, qf[ks], s0);
        s1 = mfma32(kf1, qf[ks], s1);
      }
      __builtin_amdgcn_s_setprio(0);
      if (kv0 + 63 > q0) {  // diagonal tile: causal mask (raw-score domain)
        int lim2 = q0 + l31 - kv0 - 4 * hi;
#pragma unroll
        for (int r = 0; r < 16; ++r) {
          int kc = (r & 3) + 8 * (r >> 2);
          if (kc > lim2) s0[r] = -1e30f;
          if (kc + 32 > lim2) s1[r] = -1e30f;
        }
      }
      // row max: in-lane tree over 32 + cross-half exchange
      float a[16];
#pragma unroll
      for (int r = 0; r < 16; ++r) a[r] = fmaxf(s0[r], s1[r]);
#pragma unroll
      for (int st2 = 8; st2 >= 1; st2 >>= 1)
#pragma unroll
        for (int i = 0; i < st2; ++i) a[i] = fmaxf(a[i], a[i + st2]);
      float vm = fmaxf(a[0], __shfl_xor(a[0], 32, 64));
      float p2max = vm * SCL;
      if (__any(p2max > m2 + 8.f)) {  // rare with defer-max
        float m2n = fmaxf(m2, p2max);
        float al = __builtin_amdgcn_exp2f(m2 - m2n);
        l *= al;
        m2 = m2n;
        if (lane < 32) *(float*)(wb + l31 * 4) = al;
        asm volatile("s_waitcnt lgkmcnt(0)" ::: "memory");
        f32x4 av0 = *(const f32x4*)(wb + hioff);
        f32x4 av1 = *(const f32x4*)(wb + 32 + hioff);
        f32x4 av2 = *(const f32x4*)(wb + 64 + hioff);
        f32x4 av3 = *(const f32x4*)(wb + 96 + hioff);
#pragma unroll
        for (int r = 0; r < 16; ++r) {
          float sc = (r < 4 ? av0 : r < 8 ? av1 : r < 12 ? av2 : av3)[r & 3];
          O0[r] *= sc;
          O1[r] *= sc;
        }
      }
      // P = exp2(raw*SCL - m2); per-lane partial l
#pragma unroll
      for (int r = 0; r < 16; ++r) {
        s0[r] = __builtin_amdgcn_exp2f(fmaf(s0[r], SCL, -m2));
        s1[r] = __builtin_amdgcn_exp2f(fmaf(s1[r], SCL, -m2));
      }
#pragma unroll
      for (int r = 0; r < 16; ++r) a[r] = s0[r] + s1[r];
#pragma unroll
      for (int st2 = 8; st2 >= 1; st2 >>= 1)
#pragma unroll
        for (int i = 0; i < st2; ++i) a[i] += a[i + st2];
      l += a[0];
      // pack P->bf16 A-frags (T12 pattern) and PV
      __builtin_amdgcn_s_setprio(1);
#define PV_CHUNK(SV, E, C16) { \
      unsigned x0, x1, y0, y1; \
      asm("v_cvt_pk_bf16_f32 %0, %1, %2" : "=v"(x0) : "v"(SV[8*(E)+0]), "v"(SV[8*(E)+1])); \
      asm("v_cvt_pk_bf16_f32 %0, %1, %2" : "=v"(x1) : "v"(SV[8*(E)+2]), "v"(SV[8*(E)+3])); \
      asm("v_cvt_pk_bf16_f32 %0, %1, %2" : "=v"(y0) : "v"(SV[8*(E)+4]), "v"(SV[8*(E)+5])); \
      asm("v_cvt_pk_bf16_f32 %0, %1, %2" : "=v"(y1) : "v"(SV[8*(E)+6]), "v"(SV[8*(E)+7])); \
      unsigned sy0 = __shfl_xor(y0, 32, 64), sy1 = __shfl_xor(y1, 32, 64); \
      unsigned sx0 = __shfl_xor(x0, 32, 64), sx1 = __shfl_xor(x1, 32, 64); \
      union { unsigned u[4]; bf16x8 v; } pf; \
      pf.u[0] = hi ? sy0 : x0; \
      pf.u[1] = hi ? sy1 : x1; \
      pf.u[2] = hi ? y0 : sx0; \
      pf.u[3] = hi ? y1 : sx1; \
      bf16x8 v0 = *(const bf16x8*)(VL + l31 * 128 + (((C16) * 32 + hioff) ^ swzl)); \
      bf16x8 v1 = *(const bf16x8*)(VL + (32 + l31) * 128 + (((C16) * 32 + hioff) ^ swzl)); \
      O0 = mfma32(pf.v, v0, O0); \
      O1 = mfma32(pf.v, v1, O1); }
      PV_CHUNK(s0, 0, 0)
      PV_CHUNK(s0, 1, 1)
      PV_CHUNK(s1, 0, 2)
      PV_CHUNK(s1, 1, 3)
#undef PV_CHUNK
      __builtin_amdgcn_s_setprio(0);
    }
  }
  // finalize: full row sum, broadcast 1/l, normalize, store swizzled bf16
  float lf = l + __shfl_xor(l, 32, 64);
  float rl = 1.f / lf;
  if (lane < 32) *(float*)(wb + l31 * 4) = rl;
  asm volatile("s_waitcnt lgkmcnt(0)" ::: "memory");
  f32x4 rv0 = *(const f32x4*)(wb + hioff);
  f32x4 rv1 = *(const f32x4*)(wb + 32 + hioff);
  f32x4 rv2 = *(const f32x4*)(wb + 64 + hioff);
  f32x4 rv3 = *(const f32x4*)(wb + 96 + hioff);
#pragma unroll
  for (int r = 0; r < 16; ++r) {
    float sc = (r < 4 ? rv0 : r < 8 ? rv1 : r < 12 ? rv2 : rv3)[r & 3];
    int rowl = q0 + (r & 3) + 8 * (r >> 2) + 4 * hi;
    int rowg = (b << 11) + rowl;
    int cswz = (rowl & 7) << 3;
    int cg0 = (h << 6) + l31;
    int cg1 = (h << 6) + 32 + l31;
    ansb[(size_t)rowg * 1024 + (cg0 ^ cswz)] = f2bf(O0[r] * sc);
    ansb[(size_t)rowg * 1024 + (cg1 ^ cswz)] = f2bf(O1[r] * sc);
  }
}

// ---------------------------------------------------------------------------
// Output projection (unchanged): out(fp32) = ansb(swz) * Wo^T + bo. Grid 256.
// ---------------------------------------------------------------------------
__global__ __launch_bounds__(256) void k_gemm_out(
    const unsigned short* __restrict__ ansb, const unsigned short* __restrict__ Wob,
    const float* __restrict__ bo, float* __restrict__ out) {
  __shared__ char lds[32768];
  int tid = threadIdx.x, lane = tid & 63, wid = tid >> 6;
  int bm = blockIdx.x & 31, bn = blockIdx.x >> 5;
  int r0 = bm * 128, c0 = bn * 128;
  f32x4 acc[4][4] = {};
  gemm_mainloop((const char*)ansb + (size_t)r0 * 2048,
                (const char*)Wob + (size_t)c0 * 2048, lds, lane, wid, acc);
  int g4 = lane >> 4, r16 = lane & 15, wm = wid >> 1, wn = wid & 1;
#pragma unroll
  for (int ni = 0; ni < 4; ++ni) {
    int gcol = c0 + wn * 64 + ni * 16 + r16;
    float bvv = bo[gcol];
#pragma unroll
    for (int mi = 0; mi < 4; ++mi) {
      int growb = r0 + wm * 64 + mi * 16 + g4 * 4;
#pragma unroll
      for (int jj = 0; jj < 4; ++jj)
        out[(size_t)(growb + jj) * 1024 + gcol] = acc[mi][ni][jj] + bvv;
    }
  }
}

extern "C" void kernel_launch(void* const* d_in, const int* in_sizes, int n_in,
                              void* d_out, int out_size, void* d_ws, size_t ws_size,
                              hipStream_t stream) {
  const float* x  = (const float*)d_in[0];
  const float* Wq = (const float*)d_in[1];
  const float* bq = (const float*)d_in[2];
  const float* Wk = (const float*)d_in[3];
  const float* bk = (const float*)d_in[4];
  const float* Wv = (const float*)d_in[5];
  const float* bv = (const float*)d_in[6];
  const float* Wo = (const float*)d_in[7];
  const float* bo = (const float*)d_in[8];
  char* ws = (char*)d_ws;
  unsigned short* xb   = (unsigned short*)(ws);                  // 8 MB
  unsigned short* ansb = (unsigned short*)(ws);                  // 8 MB (alias, xb dead)
  unsigned short* Wqb  = (unsigned short*)(ws + (8u  << 20));
  unsigned short* Wkb  = (unsigned short*)(ws + (10u << 20));
  unsigned short* Wvb  = (unsigned short*)(ws + (12u << 20));
  unsigned short* Wob  = (unsigned short*)(ws + (14u << 20));
  unsigned short* Qb   = (unsigned short*)(ws + (16u << 20));
  unsigned short* Kb   = (unsigned short*)(ws + (24u << 20));
  unsigned short* Vt   = (unsigned short*)(ws + (32u << 20));

  k_cvt_swz<<<2048, 256, 0, stream>>>(x,  xb,  524288);
  k_cvt_swz<<<512,  256, 0, stream>>>(Wq, Wqb, 131072);
  k_cvt_swz<<<512,  256, 0, stream>>>(Wk, Wkb, 131072);
  k_cvt_swz<<<512,  256, 0, stream>>>(Wv, Wvb, 131072);
  k_cvt_swz<<<512,  256, 0, stream>>>(Wo, Wob, 131072);
  k_gemm_qkv<<<768, 256, 0, stream>>>(xb, Wqb, Wkb, Wvb, bq, bk, bv, Qb, Kb, Vt);
  k_attn<<<512, 256, 0, stream>>>(Qb, Kb, Vt, ansb);
  k_gemm_out<<<256, 256, 0, stream>>>(ansb, Wob, bo, (float*)d_out);
}